// Round 3
// baseline (128.034 us; speedup 1.0000x reference)
//
#include <hip/hip_runtime.h>

#define HD 64       // HIDDEN_DIM
#define NE 512      // N_EMBEDS
#define HW 1024     // 32*32 spatial positions per batch image

typedef float f32x2  __attribute__((ext_vector_type(2)));
typedef float f32x4  __attribute__((ext_vector_type(4)));
typedef float f32x16 __attribute__((ext_vector_type(16)));

// ---------------------------------------------------------------------------
// Prep (130 blocks x 256):
//  blk 0..127 : epT[c][k] = -2 * e[k][c]   (transposed, code-major rows)
//  blk 128/129: esq[k] = np.sum(e[k]*e[k]), numpy pairwise-8, no contraction.
//  Verified absmax==0.0 R1-R13.
// ---------------------------------------------------------------------------
__global__ __launch_bounds__(256) void vq_prep_kernel(const float* __restrict__ e,
                                                      float* __restrict__ epT,
                                                      float* __restrict__ esq) {
  const int blk = blockIdx.x;
  if (blk < 128) {
    const int t = blk * 256 + threadIdx.x;     // 0..32767
    const int c = t >> 9, k = t & 511;
    epT[t] = -2.0f * e[k * HD + c];
  } else {
    const int k = (blk - 128) * 256 + threadIdx.x;   // 0..511
    const float4* __restrict__ rowv = reinterpret_cast<const float4*>(e + k * HD);
    float row[HD];
    #pragma unroll
    for (int i = 0; i < 16; ++i) {
      const float4 v = rowv[i];
      row[4 * i + 0] = v.x; row[4 * i + 1] = v.y;
      row[4 * i + 2] = v.z; row[4 * i + 3] = v.w;
    }
    float result;
    {
      #pragma clang fp contract(off)
      float r[8];
      #pragma unroll
      for (int j = 0; j < 8; ++j) r[j] = row[j] * row[j];
      #pragma unroll
      for (int i = 8; i < HD; i += 8) {
        #pragma unroll
        for (int j = 0; j < 8; ++j) r[j] = r[j] + row[i + j] * row[i + j];
      }
      result = ((r[0] + r[1]) + (r[2] + r[3])) + ((r[4] + r[5]) + (r[6] + r[7]));
    }
    esq[k] = result;
  }
}

// ---------------------------------------------------------------------------
// Main R14: 2048 blocks x 256 (4 waves). Block = 32 positions x 512 codes.
//
// R13 counters: VALU busy ~33-38us constant across R11-R13 => v_pk_fma_f32 is
// half-rate on gfx950 (fp32 FLOP floor = 27.3us, matching the 157.3TF spec).
// The "s"-constraint x path generated v_readfirstlane x32/c (~6.8us VALU) and
// acc2[8][8] (128 regs, hidden in the unified AGPR file) capped occupancy at
// ~2-3 waves/SIMD (22.7% measured), exposing x-load + DMA latency (~24us).
//
// R14 fixes all three:
//  - wave = 16 pos x 256 codes: acc = 64 VGPRs, total ~118 -> 4 waves/SIMD.
//    x stays wave-uniform but is loaded as a plain VECTOR load (replicated
//    uniform value, "v" asm constraints -> zero readfirstlanes), depth-2
//    ping-pong prefetch. e: ONE conflict-free ds_read_b128 per wave-c.
//  - DMA double-buffer, issue-ahead-by-one: issue chunk ch+1 after the
//    barrier, compute ch; next iter's __syncthreads drains a DMA that had a
//    full compute phase to land. 1 barrier/chunk, latency hidden.
//  - combine scratch overlays the 32KB chunk pool (rotated slots, minimum
//    LDS aliasing), lexicographic (d,idx) == np.argmin first-index-wins.
//
// Bit-exactness: one IEEE fp32 fma per (pos,code,c), c ascending 0..63 (pk
// halves = independent positions, e broadcast via op_sel — R11-R13-verified
// encoding); xsq/esq numpy pairwise-8 trees identical; (xsq+esq)+acc
// distance identical.
// ---------------------------------------------------------------------------
__global__ __launch_bounds__(256)
__attribute__((amdgpu_waves_per_eu(4)))
void vq_main_kernel(const float* __restrict__ x,
                    const float* __restrict__ epT,
                    const float* __restrict__ esq,
                    const float* __restrict__ e,
                    float* __restrict__ out) {
  // pool: 2 x 4096-word chunk buffers (compute) / combine scratch (epilogue)
  __shared__ __align__(16) float pool[8192];   // 32 KB
  __shared__ float part[512];                  // 2 KB  [w][qq][pi] (d,idx)
  __shared__ float wbest[128];                 // [w][pi] (d,idx) pairs
  __shared__ float sp[256];                    // [g][pos] xsq chain partials
  __shared__ float xsq[32];
  __shared__ int   bcomb[32];

  const int t    = threadIdx.x;
  const int lane = t & 63;
  const int wq   = __builtin_amdgcn_readfirstlane(t >> 6);   // 0..3
  const int kh   = wq & 1;             // code half   (256 codes)
  const int wp   = wq >> 1;            // pos half    (16 positions)
  const int eoff = 4 * lane;           // lane's 4 codes within the half

  const int blk = blockIdx.x;          // 2048
  const int b   = blk >> 5;
  const int s0  = (blk & 31) << 5;
  const size_t xbase = (size_t)b * (HD * HW) + s0;

  const float4* __restrict__ g4 = reinterpret_cast<const float4*>(epT);

  // ---- DMA issue: chunk ch (8 c x 512 codes = 16 KB) into buf[ch&1]
#define ISSUE(ch_) do {                                                      \
    float4* dst_ = reinterpret_cast<float4*>(pool + (((ch_) & 1) << 12));    \
    _Pragma("unroll")                                                        \
    for (int i_ = 0; i_ < 4; ++i_)                                           \
      __builtin_amdgcn_global_load_lds(                                      \
          (const __attribute__((address_space(1))) void*)(g4 + (size_t)(ch_) * 1024 + i_ * 256 + t), \
          (__attribute__((address_space(3))) void*)(dst_ + i_ * 256 + t),    \
          16, 0, 0);                                                         \
  } while (0)

  ISSUE(0);                            // first chunk in flight

  // ---- xsq chain partials: thread (pos=t&31, g=t>>5) runs numpy chain r[g]
  {
    #pragma clang fp contract(off)
    const int pos = t & 31, g = t >> 5;          // g 0..7
    const float* __restrict__ xp0 = x + xbase + pos;
    float v = xp0[(size_t)g * HW];
    float r = v * v;
    #pragma unroll
    for (int m = 1; m < 8; ++m) {
      v = xp0[(size_t)(g + 8 * m) * HW];
      r = r + v * v;
    }
    sp[g * 32 + pos] = r;              // r[g]
  }

  // ---- accumulator: acc2[pos-pair][code j] == -2*cross (fma chain over c)
  f32x2 acc2[8][4];                    // 64 VGPRs
  #pragma unroll
  for (int pp = 0; pp < 8; ++pp)
    #pragma unroll
    for (int j = 0; j < 4; ++j) acc2[pp][j] = (f32x2)(0.f);

  const float* __restrict__ xw = x + xbase + wp * 16;   // wave's 16 positions
  f32x16 xv0 = *reinterpret_cast<const f32x16*>(xw);
  f32x16 xv1 = *reinterpret_cast<const f32x16*>(xw + HW);

  // one pk_fma per (pos-pair, code); e broadcast via op_sel (R11-verified)
#define PKROW(XV) do {                                                        \
    _Pragma("unroll")                                                         \
    for (int pp = 0; pp < 8; ++pp) {                                          \
      const f32x2 xp = (f32x2){(XV)[2 * pp], (XV)[2 * pp + 1]};               \
      asm("v_pk_fma_f32 %0, %1, %2, %0 op_sel:[0,0,0] op_sel_hi:[1,0,1]"      \
          : "+v"(acc2[pp][0]) : "v"(xp), "v"(ep0));                           \
      asm("v_pk_fma_f32 %0, %1, %2, %0 op_sel:[0,1,0] op_sel_hi:[1,1,1]"      \
          : "+v"(acc2[pp][1]) : "v"(xp), "v"(ep0));                           \
      asm("v_pk_fma_f32 %0, %1, %2, %0 op_sel:[0,0,0] op_sel_hi:[1,0,1]"      \
          : "+v"(acc2[pp][2]) : "v"(xp), "v"(ep1));                           \
      asm("v_pk_fma_f32 %0, %1, %2, %0 op_sel:[0,1,0] op_sel_hi:[1,1,1]"      \
          : "+v"(acc2[pp][3]) : "v"(xp), "v"(ep1));                           \
    }                                                                         \
  } while (0)

  #pragma unroll 1
  for (int ch = 0; ch < 8; ++ch) {
    __syncthreads();                   // drains DMA(ch) (hidden under prev
                                       // compute); frees buf[(ch+1)&1]
    if (ch < 7) ISSUE(ch + 1);         // in flight across this compute phase
    if (ch == 0 && t < 32) {           // finish xsq tree (numpy pairwise-8)
      #pragma clang fp contract(off)
      xsq[t] = ((sp[t] + sp[32 + t]) + (sp[64 + t] + sp[96 + t])) +
               ((sp[128 + t] + sp[160 + t]) + (sp[192 + t] + sp[224 + t]));
    }
    const float* __restrict__ esc = pool + ((ch & 1) << 12) + kh * 256 + eoff;
    #pragma unroll
    for (int cc = 0; cc < 8; ++cc) {
      const int c   = ch * 8 + cc;
      const int cpf = (c + 2) & 63;    // wrap keeps addresses in-bounds
      const f32x4 ev = *reinterpret_cast<const f32x4*>(esc + cc * NE);
      const f32x2 ep0 = ev.lo, ep1 = ev.hi;
      if ((cc & 1) == 0) {
        PKROW(xv0);
        xv0 = *reinterpret_cast<const f32x16*>(xw + (size_t)cpf * HW);
      } else {
        PKROW(xv1);
        xv1 = *reinterpret_cast<const f32x16*>(xw + (size_t)cpf * HW);
      }
    }
  }
  __syncthreads();                     // all es reads done; overlay combine

#undef PKROW
#undef ISSUE

  // ---- per-lane argmin over its 4 codes -> rotated-slot combine scratch.
  //      code = kh*256 + 4*lane + j, ascending j == first-index-wins.
  const f32x4 eq = *reinterpret_cast<const f32x4*>(esq + kh * 256 + eoff);
  const int kbase = kh * 256 + eoff;
  float* cw = pool + wq * 2048;        // per-wave region [pi][slot]
  #pragma unroll
  for (int pi = 0; pi < 16; ++pi) {
    const float xq = xsq[wp * 16 + pi];
    const int pp = pi >> 1, ph = pi & 1;
    float bd = __builtin_inff();
    int   bi = 0x7fffffff;
    #pragma unroll
    for (int j = 0; j < 4; ++j) {
      const float d = (xq + eq[j]) + acc2[pp][j][ph];
      if (d < bd) { bd = d; bi = kbase + j; }
    }
    const int slot = (lane + pi) & 63; // rotation: min-aliasing banks
    *reinterpret_cast<f32x2*>(cw + pi * 128 + slot * 2) =
        (f32x2){bd, __int_as_float(bi)};
  }

  // ---- within-wave reduce (same-wave LDS ops in-order; no barrier).
  //      Lexicographic (d,idx) at every merge == np.argmin semantics.
  {
    const int pi = lane & 15, qq = lane >> 4;
    float bd = __builtin_inff();
    int   bi = 0x7fffffff;
    #pragma unroll
    for (int i = 0; i < 16; ++i) {
      const int slot = (qq * 16 + i + pi) & 63;   // rotated read, bijective
      const f32x2 pr = *reinterpret_cast<const f32x2*>(cw + pi * 128 + slot * 2);
      const float d = pr[0];
      const int idx = __float_as_int(pr[1]);
      if (d < bd || (d == bd && idx < bi)) { bd = d; bi = idx; }
    }
    *reinterpret_cast<f32x2*>(part + ((wq * 4 + qq) * 16 + pi) * 2) =
        (f32x2){bd, __int_as_float(bi)};
    if (lane < 16) {                   // merge 4 quarters -> wave best
      float bd2 = __builtin_inff();
      int   bi2 = 0x7fffffff;
      #pragma unroll
      for (int q2 = 0; q2 < 4; ++q2) {
        const f32x2 pr = *reinterpret_cast<const f32x2*>(part + ((wq * 4 + q2) * 16 + lane) * 2);
        const float d = pr[0];
        const int idx = __float_as_int(pr[1]);
        if (d < bd2 || (d == bd2 && idx < bi2)) { bd2 = d; bi2 = idx; }
      }
      *reinterpret_cast<f32x2*>(wbest + (wq * 16 + lane) * 2) =
          (f32x2){bd2, __int_as_float(bi2)};
    }
  }
  __syncthreads();

  // ---- merge the two code-halves per position (t<32: one thread per pos)
  if (t < 32) {
    const int wp_ = t >> 4, pi_ = t & 15;
    const f32x2 a = *reinterpret_cast<const f32x2*>(wbest + ((2 * wp_ + 0) * 16 + pi_) * 2);
    const f32x2 bq = *reinterpret_cast<const f32x2*>(wbest + ((2 * wp_ + 1) * 16 + pi_) * 2);
    const float da = a[0], db = bq[0];
    const int ia = __float_as_int(a[1]), ib = __float_as_int(bq[1]);
    bcomb[t] = (db < da || (db == da && ib < ia)) ? ib : ia;
  }
  __syncthreads();

  // ---- gather winning codebook rows (L2-hot), coalesced stores
  {
    const int pos = t & 31, cr = t >> 5;
    const int idx = bcomb[pos];
    const float* __restrict__ eqr = e + idx * HD;
    #pragma unroll
    for (int i = 0; i < 8; ++i) {
      const int c = cr + 8 * i;
      out[xbase + (size_t)c * HW + pos] = eqr[c];
    }
  }
}

extern "C" void kernel_launch(void* const* d_in, const int* in_sizes, int n_in,
                              void* d_out, int out_size, void* d_ws, size_t ws_size,
                              hipStream_t stream) {
  const float* x = (const float*)d_in[0];   // (64, 64, 32, 32) fp32
  const float* e = (const float*)d_in[1];   // (512, 64) fp32
  float* epT = (float*)d_ws;                // 64*512 floats: -2*e transposed
  float* esq = epT + HD * NE;               // 512 floats
  float* out = (float*)d_out;

  vq_prep_kernel<<<130, 256, 0, stream>>>(e, epT, esq);
  vq_main_kernel<<<2048, 256, 0, stream>>>(x, epT, esq, e, out);
}

// Round 7
// 121.096 us; speedup vs baseline: 1.0573x; 1.0573x over previous
//
#include <hip/hip_runtime.h>

#define HD 64       // HIDDEN_DIM
#define NE 512      // N_EMBEDS
#define HW 1024     // 32*32 spatial positions per batch image

typedef float f32x2  __attribute__((ext_vector_type(2)));
typedef float f32x4  __attribute__((ext_vector_type(4)));
typedef float f32x16 __attribute__((ext_vector_type(16)));

// ---------------------------------------------------------------------------
// Prep (130 blocks x 256):
//  blk 0..127 : epT[c][k] = -2 * e[k][c]   (transposed, code-major rows)
//  blk 128/129: esq[k] = np.sum(e[k]*e[k]), numpy pairwise-8, no contraction.
//  Verified absmax==0.0 R1-R14.
// ---------------------------------------------------------------------------
__global__ __launch_bounds__(256) void vq_prep_kernel(const float* __restrict__ e,
                                                      float* __restrict__ epT,
                                                      float* __restrict__ esq) {
  const int blk = blockIdx.x;
  if (blk < 128) {
    const int t = blk * 256 + threadIdx.x;     // 0..32767
    const int c = t >> 9, k = t & 511;
    epT[t] = -2.0f * e[k * HD + c];
  } else {
    const int k = (blk - 128) * 256 + threadIdx.x;   // 0..511
    const float4* __restrict__ rowv = reinterpret_cast<const float4*>(e + k * HD);
    float row[HD];
    #pragma unroll
    for (int i = 0; i < 16; ++i) {
      const float4 v = rowv[i];
      row[4 * i + 0] = v.x; row[4 * i + 1] = v.y;
      row[4 * i + 2] = v.z; row[4 * i + 3] = v.w;
    }
    float result;
    {
      #pragma clang fp contract(off)
      float r[8];
      #pragma unroll
      for (int j = 0; j < 8; ++j) r[j] = row[j] * row[j];
      #pragma unroll
      for (int i = 8; i < HD; i += 8) {
        #pragma unroll
        for (int j = 0; j < 8; ++j) r[j] = r[j] + row[i + j] * row[i + j];
      }
      result = ((r[0] + r[1]) + (r[2] + r[3])) + ((r[4] + r[5]) + (r[6] + r[7]));
    }
    esq[k] = result;
  }
}

// ---------------------------------------------------------------------------
// Main R17: 1024 blocks x 512 threads (8 waves). Block = 64 pos x 512 codes.
//
// R16 hit two consecutive container failures (no kernel signal). The design
// was HW-validated bit-exact in R15 (error == exactly 1/512 == zeros on the
// uncovered half; computed half bit-exact). R17 keeps the validated design
// and hedges the launch geometry: 512-thread blocks, wave wq owns 64 codes
// [64wq, 64wq+64) — structurally equivalent, different binary shape.
//
// Design (from R13/R14 counter analysis): true fma floor is 27.3us (2.15e9
// MACs at 32/cyc/SIMD; pk_fma has NO fp32 throughput gain on gfx950). Every
// inner-loop VALU op is a dense v_fmac_f32:
//  - lane = position (64 pos/wave, all waves same 64 positions). x: ONE
//    coalesced global dword per wave-c.
//  - e is wave-uniform -> SCALAR pipe: 4x s_load_dwordx16 (one 256B c-row)
//    + s_waitcnt lgkmcnt(0) fused in ONE volatile asm block, early-clobber
//    outputs; consumers read the asm outputs -> dataflow-ordered.
//    fmac = v_fmac_f32 vacc, s[e], v[x]: zero movs, zero LDS, zero
//    vector-VMEM for e, no barriers in the main loop.
//  - per-c latency: ~200cyc K$/L2 wait vs ~132cyc compute; 4 waves/SIMD
//    (2 blocks/CU, acc[64]+misc ~92 VGPR) cover it via TLP.
//  - xsq folded per-lane into the c-loop (r[8] chains, contract off, exact
//    numpy pairwise-8; 0 + v*v == v*v bitwise).
//
// Bit-exactness: acc[k] = fma(epT_val, x_val, acc[k]) over c ascending
// (IEEE-commutative operand order, same chain as R11-R15-verified);
// distance (xsq + esq[k]) + acc[k] association identical; within-lane
// strict < over ascending codes == first-index-wins; cross-wave
// lexicographic (d, idx) merge (ascending wave == ascending code range)
// == np.argmin first-occurrence semantics.
// ---------------------------------------------------------------------------
__global__ __launch_bounds__(512)
__attribute__((amdgpu_waves_per_eu(4)))
void vq_main_kernel(const float* __restrict__ x,
                    const float* __restrict__ epT,
                    const float* __restrict__ esq,
                    const float* __restrict__ e,
                    float* __restrict__ out) {
  __shared__ f32x2 scr[8 * 64];        // 4 KB: per-wave per-pos (d, idx)
  __shared__ int   bcomb[64];

  const int t    = threadIdx.x;
  const int lane = t & 63;                                  // = position
  const int wq   = __builtin_amdgcn_readfirstlane(t >> 6);  // 0..7 code slot

  const int blk = blockIdx.x;          // 1024
  const int b   = blk >> 4;            // image 0..63
  const int win = blk & 15;            // 64-position window 0..15
  const size_t xbase = (size_t)b * (HD * HW) + (size_t)win * 64;

  const float* __restrict__ xw = x + xbase + lane;
  const unsigned long long ebase =
      (unsigned long long)(const void*)epT + (unsigned)wq * 256u;

  float acc[64];                       // -2*cross accumulators (codes)
  #pragma unroll
  for (int k = 0; k < 64; ++k) acc[k] = 0.f;
  float r[8];                          // xsq pairwise-8 chain partials
  #pragma unroll
  for (int j = 0; j < 8; ++j) r[j] = 0.f;

  #pragma unroll 1
  for (int C = 0; C < 64; C += 8) {
    // x for this 8-c block: per-lane coalesced dwords (compiler pipelines)
    float xv[8];
    #pragma unroll
    for (int j = 0; j < 8; ++j) xv[j] = xw[(size_t)(C + j) * HW];

    #pragma unroll
    for (int cc = 0; cc < 8; ++cc) {   // one 256B c-row per scalar asm block
      f32x16 e0, e1, e2, e3;
      const unsigned long long ea =
          ebase + (unsigned)((C + cc) * (NE * 4));
      asm volatile(
          "s_load_dwordx16 %0, %4, 0\n\t"
          "s_load_dwordx16 %1, %4, 0x40\n\t"
          "s_load_dwordx16 %2, %4, 0x80\n\t"
          "s_load_dwordx16 %3, %4, 0xC0\n\t"
          "s_waitcnt lgkmcnt(0)"
          : "=&s"(e0), "=&s"(e1), "=&s"(e2), "=&s"(e3)
          : "s"(ea));

      const float xc = xv[cc];
      {
        #pragma clang fp contract(off)
        const float sq = xc * xc;
        r[cc] = r[cc] + sq;            // chain index = c mod 8 (exact numpy)
      }
      #pragma unroll
      for (int k = 0; k < 16; ++k)
        acc[k] = __builtin_fmaf(e0[k], xc, acc[k]);
      #pragma unroll
      for (int k = 0; k < 16; ++k)
        acc[16 + k] = __builtin_fmaf(e1[k], xc, acc[16 + k]);
      #pragma unroll
      for (int k = 0; k < 16; ++k)
        acc[32 + k] = __builtin_fmaf(e2[k], xc, acc[32 + k]);
      #pragma unroll
      for (int k = 0; k < 16; ++k)
        acc[48 + k] = __builtin_fmaf(e3[k], xc, acc[48 + k]);
    }
  }

  // ---- xsq finish: numpy pairwise-8 tree (contract off), per lane
  float xsql;
  {
    #pragma clang fp contract(off)
    xsql = ((r[0] + r[1]) + (r[2] + r[3])) + ((r[4] + r[5]) + (r[6] + r[7]));
  }

  // ---- esq slice for this wave's 64 codes (scalar pipe, same asm pattern)
  f32x16 q0, q1, q2, q3;
  {
    const unsigned long long qa =
        (unsigned long long)(const void*)esq + (unsigned)wq * 256u;
    asm volatile(
        "s_load_dwordx16 %0, %4, 0\n\t"
        "s_load_dwordx16 %1, %4, 0x40\n\t"
        "s_load_dwordx16 %2, %4, 0x80\n\t"
        "s_load_dwordx16 %3, %4, 0xC0\n\t"
        "s_waitcnt lgkmcnt(0)"
        : "=&s"(q0), "=&s"(q1), "=&s"(q2), "=&s"(q3)
        : "s"(qa));
  }

  // ---- per-lane argmin over the wave's 64 codes (ascending: first-wins)
  float bd = __builtin_inff();
  int   bi = 0x7fffffff;
  const int kb = wq * 64;
  #pragma unroll
  for (int k = 0; k < 16; ++k) {
    const float d = (xsql + q0[k]) + acc[k];
    if (d < bd) { bd = d; bi = kb + k; }
  }
  #pragma unroll
  for (int k = 0; k < 16; ++k) {
    const float d = (xsql + q1[k]) + acc[16 + k];
    if (d < bd) { bd = d; bi = kb + 16 + k; }
  }
  #pragma unroll
  for (int k = 0; k < 16; ++k) {
    const float d = (xsql + q2[k]) + acc[32 + k];
    if (d < bd) { bd = d; bi = kb + 32 + k; }
  }
  #pragma unroll
  for (int k = 0; k < 16; ++k) {
    const float d = (xsql + q3[k]) + acc[48 + k];
    if (d < bd) { bd = d; bi = kb + 48 + k; }
  }

  scr[wq * 64 + lane] = (f32x2){bd, __int_as_float(bi)};
  __syncthreads();

  // ---- cross-wave merge: ascending wave == ascending code ranges;
  //      lexicographic (d, idx) == np.argmin first-occurrence.
  if (t < 64) {
    f32x2 p = scr[t];
    float bd2 = p[0];
    int   bi2 = __float_as_int(p[1]);
    #pragma unroll
    for (int w2 = 1; w2 < 8; ++w2) {
      const f32x2 pr = scr[w2 * 64 + t];
      const float d = pr[0];
      const int  ix = __float_as_int(pr[1]);
      if (d < bd2 || (d == bd2 && ix < bi2)) { bd2 = d; bi2 = ix; }
    }
    bcomb[t] = bi2;
  }
  __syncthreads();

  // ---- gather winning codebook rows (L2-hot), coalesced stores
  {
    const int pos = t & 63, cg = t >> 6;      // cg 0..7 -> 8 c's each
    const int idx = bcomb[pos];
    const f32x4 ev0 = *reinterpret_cast<const f32x4*>(e + idx * HD + cg * 8);
    const f32x4 ev1 = *reinterpret_cast<const f32x4*>(e + idx * HD + cg * 8 + 4);
    #pragma unroll
    for (int i = 0; i < 4; ++i)
      out[xbase + (size_t)(cg * 8 + i) * HW + pos] = ev0[i];
    #pragma unroll
    for (int i = 0; i < 4; ++i)
      out[xbase + (size_t)(cg * 8 + 4 + i) * HW + pos] = ev1[i];
  }
}

extern "C" void kernel_launch(void* const* d_in, const int* in_sizes, int n_in,
                              void* d_out, int out_size, void* d_ws, size_t ws_size,
                              hipStream_t stream) {
  const float* x = (const float*)d_in[0];   // (64, 64, 32, 32) fp32
  const float* e = (const float*)d_in[1];   // (512, 64) fp32
  float* epT = (float*)d_ws;                // 64*512 floats: -2*e transposed
  float* esq = epT + HD * NE;               // 512 floats
  float* out = (float*)d_out;

  vq_prep_kernel<<<130, 256, 0, stream>>>(e, epT, esq);
  vq_main_kernel<<<1024, 512, 0, stream>>>(x, epT, esq, e, out);
}